// Round 1
// baseline (1069.238 us; speedup 1.0000x reference)
//
#include <hip/hip_runtime.h>
#include <math.h>

#define N_NODES 50000
#define N_EDGES 800000
#define ET (N_EDGES + N_NODES)      // 850000 edges incl. self-loops
#define IN_DIM 128
#define HID 64
#define HEADS 4
#define D1 256                      // HID*HEADS
#define NCLS 40
#define NEG_SLOPE 0.2f
#define BN_EPS 1e-5f
#define SM_EPS 1e-16f

__device__ __forceinline__ float eluf(float x) { return x > 0.f ? x : expm1f(x); }
__device__ __forceinline__ float lrelu(float x) { return x >= 0.f ? x : NEG_SLOPE * x; }

// ---------------------------------------------------------------- CSR build
__global__ void k_deg(const int* __restrict__ ei, int* __restrict__ deg) {
    int e = blockIdx.x * blockDim.x + threadIdx.x;
    if (e >= ET) return;
    int dst = (e < N_EDGES) ? ei[N_EDGES + e] : (e - N_EDGES);
    atomicAdd(&deg[dst], 1);
}

// single-block exclusive scan (wave shuffle scan + cross-wave LDS), 1024 thr
__global__ __launch_bounds__(1024) void k_scan(const int* __restrict__ deg,
                                               int* __restrict__ row_start,
                                               int* __restrict__ cursor) {
    __shared__ int wsum[16];
    __shared__ int chunk_tot;
    __shared__ int carry_sh;
    const int t = threadIdx.x;
    const int w = t >> 6, lane = t & 63;
    if (t == 0) carry_sh = 0;
    __syncthreads();
    for (int base = 0; base < N_NODES; base += 1024) {
        const int idx = base + t;
        int v = (idx < N_NODES) ? deg[idx] : 0;
        int s = v;                       // inclusive wave scan
        #pragma unroll
        for (int off = 1; off < 64; off <<= 1) {
            int y = __shfl_up(s, off, 64);
            if (lane >= off) s += y;
        }
        if (lane == 63) wsum[w] = s;
        __syncthreads();
        if (t < 16) {                    // scan the 16 wave totals
            int x = wsum[t];
            int sc = x;
            #pragma unroll
            for (int off = 1; off < 16; off <<= 1) {
                int y = __shfl_up(sc, off, 64);
                if (t >= off) sc += y;
            }
            wsum[t] = sc - x;            // exclusive wave offset
            if (t == 15) chunk_tot = sc;
        }
        __syncthreads();
        const int excl = carry_sh + wsum[w] + (s - v);
        if (idx < N_NODES) { row_start[idx] = excl; cursor[idx] = excl; }
        __syncthreads();
        if (t == 0) carry_sh += chunk_tot;
        // next iteration's barriers order this write before its readers
    }
    __syncthreads();
    if (t == 0) row_start[N_NODES] = carry_sh;
}

__global__ void k_scatter(const int* __restrict__ ei, int* __restrict__ cursor,
                          int* __restrict__ csr_src) {
    int e = blockIdx.x * blockDim.x + threadIdx.x;
    if (e >= ET) return;
    int src, dst;
    if (e < N_EDGES) { src = ei[e]; dst = ei[N_EDGES + e]; }
    else             { src = dst = e - N_EDGES; }
    int pos = atomicAdd(&cursor[dst], 1);
    csr_src[pos] = src;
}

// ---------------------------------------------------------------- GEMM
// C[M x ncols] = op(A[M x K]) @ [B1 | B2]   (B1,B2 each K x w, ncols = 2w)
// op = identity, or fused batchnorm-affine + ELU when fuse != 0.
#define GBM 128
#define GBN 128
#define GBK 16
__global__ __launch_bounds__(256) void k_gemm(
    const float* __restrict__ A, const float* __restrict__ B1,
    const float* __restrict__ B2, float* __restrict__ C,
    int M, int K, int w, int ncols,
    const float* __restrict__ bn_g, const float* __restrict__ bn_b, int fuse)
{
    __shared__ float As[GBK][GBM + 4];
    __shared__ float Bs[GBK][GBN + 4];
    __shared__ float gsh[256], bsh[256];
    const int t = threadIdx.x;
    const int i0 = blockIdx.x * GBM;
    const int j0 = blockIdx.y * GBN;
    if (fuse && t < K) { gsh[t] = bn_g[t]; bsh[t] = bn_b[t]; }
    __syncthreads();

    float acc[8][8];
    #pragma unroll
    for (int a = 0; a < 8; a++)
        #pragma unroll
        for (int b = 0; b < 8; b++) acc[a][b] = 0.f;
    const int tm = (t >> 4) * 8;
    const int tn = (t & 15) * 8;

    for (int kt = 0; kt < K; kt += GBK) {
        // A tile 128x16, float4 loads
        #pragma unroll
        for (int i = 0; i < 2; i++) {
            int f = t + i * 256;          // 0..511
            int m = f >> 2;
            int kq = (f & 3) << 2;
            int row = i0 + m;
            float4 v = make_float4(0.f, 0.f, 0.f, 0.f);
            if (row < M) v = *(const float4*)&A[(size_t)row * K + kt + kq];
            if (fuse) {
                int k = kt + kq;
                v.x = eluf(gsh[k + 0] * v.x + bsh[k + 0]);
                v.y = eluf(gsh[k + 1] * v.y + bsh[k + 1]);
                v.z = eluf(gsh[k + 2] * v.z + bsh[k + 2]);
                v.w = eluf(gsh[k + 3] * v.w + bsh[k + 3]);
            }
            As[kq + 0][m] = v.x; As[kq + 1][m] = v.y;
            As[kq + 2][m] = v.z; As[kq + 3][m] = v.w;
        }
        // B tile 16x128 scalar (handles B1|B2 split + ncols padding)
        #pragma unroll
        for (int i = 0; i < 8; i++) {
            int f = t + i * 256;          // 0..2047
            int kk = f >> 7;
            int j = f & 127;
            int col = j0 + j;
            float v = 0.f;
            if (col < ncols) {
                int kg = kt + kk;
                v = (col < w) ? B1[(size_t)kg * w + col]
                              : B2[(size_t)kg * w + (col - w)];
            }
            Bs[kk][j] = v;
        }
        __syncthreads();
        #pragma unroll
        for (int kk = 0; kk < GBK; kk++) {
            float4 a0 = *(const float4*)&As[kk][tm];
            float4 a1 = *(const float4*)&As[kk][tm + 4];
            float4 b0 = *(const float4*)&Bs[kk][tn];
            float4 b1 = *(const float4*)&Bs[kk][tn + 4];
            float av[8] = {a0.x, a0.y, a0.z, a0.w, a1.x, a1.y, a1.z, a1.w};
            float bv[8] = {b0.x, b0.y, b0.z, b0.w, b1.x, b1.y, b1.z, b1.w};
            #pragma unroll
            for (int a = 0; a < 8; a++)
                #pragma unroll
                for (int b = 0; b < 8; b++) acc[a][b] += av[a] * bv[b];
        }
        __syncthreads();
    }
    #pragma unroll
    for (int a = 0; a < 8; a++) {
        int row = i0 + tm + a;
        if (row >= M) continue;
        #pragma unroll
        for (int b = 0; b < 8; b += 4) {
            int col = j0 + tn + b;
            if (col + 3 < ncols) {
                *(float4*)&C[(size_t)row * ncols + col] =
                    make_float4(acc[a][b], acc[a][b + 1], acc[a][b + 2], acc[a][b + 3]);
            }
            // cols >= ncols are padding; nothing to store
        }
    }
}

// ---------------------------------------------------------------- layer-1 node kernel
// One block (256 thr = 4 waves) per dst node. Flash-style online segment
// softmax; xl[src] rows staged in LDS once per chunk, used for both the
// logit and the aggregation. thread t: head h = t>>6, channel c = t&63.
#define CH1 16
__global__ __launch_bounds__(256) void k_node1(
    const float* __restrict__ xlr, const int* __restrict__ row_start,
    const int* __restrict__ csr_src, const float* __restrict__ att1,
    const float* __restrict__ b1, float* __restrict__ h1)
{
    __shared__ float xl_sh[CH1][D1];    // 16 KB
    __shared__ float xr_sh[D1];
    __shared__ float p_sh[CH1][HEADS];
    __shared__ int src_sh[CH1];
    const int i = blockIdx.x;
    const int t = threadIdx.x;
    const int h = t >> 6, lane = t & 63;
    const int s0 = row_start[i], s1 = row_start[i + 1];
    xr_sh[t] = xlr[(size_t)i * 512 + 256 + t];
    const float att = att1[t];          // att1[h*64 + c] == att1[t]
    const float bvv = b1[t];
    float acc = 0.f;
    float m_run = -__builtin_inff(), l_run = 0.f;   // wave-uniform per head
    __syncthreads();

    for (int base = s0; base < s1; base += CH1) {
        const int cnt = min(CH1, s1 - base);
        if (t < cnt) src_sh[t] = csr_src[base + t];
        __syncthreads();                 // also protects xl_sh from prev chunk readers
        for (int e = 0; e < cnt; e++)
            xl_sh[e][t] = xlr[(size_t)src_sh[e] * 512 + t];
        __syncthreads();
        // pass 1: logits per (edge, head); wave h reduces its 64 channels
        float m_chunk = -__builtin_inff();
        for (int e = 0; e < cnt; e++) {
            float v = lrelu(xl_sh[e][t] + xr_sh[t]) * att;
            #pragma unroll
            for (int off = 32; off; off >>= 1) v += __shfl_xor(v, off, 64);
            if (lane == 0) p_sh[e][h] = v;   // wave-local stash
            m_chunk = fmaxf(m_chunk, v);
        }
        const float m_new = fmaxf(m_run, m_chunk);
        const float scale = __expf(m_run - m_new);   // exp(-inf)=0 first time
        acc *= scale;
        float lsum = 0.f;
        for (int e = 0; e < cnt; e++) {
            float p = __expf(p_sh[e][h] - m_new);
            lsum += p;
            if (lane == 0) p_sh[e][h] = p;
        }
        l_run = l_run * scale + lsum;
        m_run = m_new;
        // p_sh/xl_sh only read by the wave that wrote p_sh; xl_sh covered by
        // the barrier above — no extra barrier needed before aggregation.
        for (int e = 0; e < cnt; e++)
            acc += p_sh[e][h] * xl_sh[e][t];
    }
    h1[(size_t)i * 256 + t] = acc / (l_run + SM_EPS) + bvv;
}

// ---------------------------------------------------------------- batchnorm
__global__ void k_bnstats(const float* __restrict__ h1, float* __restrict__ bn_sum,
                          float* __restrict__ bn_sumsq) {
    const int t = threadIdx.x;           // 256 = one feature per thread
    const int rows_per = (N_NODES + gridDim.x - 1) / gridDim.x;
    const int r0 = blockIdx.x * rows_per;
    const int r1 = min(N_NODES, r0 + rows_per);
    float s = 0.f, s2 = 0.f;
    for (int r = r0; r < r1; r++) {
        float v = h1[(size_t)r * 256 + t];
        s += v; s2 += v * v;
    }
    atomicAdd(&bn_sum[t], s);
    atomicAdd(&bn_sumsq[t], s2);
}

__global__ void k_bnfinal(const float* __restrict__ bn_sum, const float* __restrict__ bn_sumsq,
                          const float* __restrict__ gamma, const float* __restrict__ beta,
                          float* __restrict__ bn_g, float* __restrict__ bn_b) {
    const int t = threadIdx.x;
    float mean = bn_sum[t] * (1.f / N_NODES);
    float var = bn_sumsq[t] * (1.f / N_NODES) - mean * mean;
    float g = gamma[t] * rsqrtf(var + BN_EPS);
    bn_g[t] = g;
    bn_b[t] = beta[t] - g * mean;
}

// ---------------------------------------------------------------- layer-2 node kernel
// One wave per dst node (4 nodes per block); 40 classes live in lanes 0..39.
__global__ __launch_bounds__(256) void k_node2(
    const float* __restrict__ xlr2, const int* __restrict__ row_start,
    const int* __restrict__ csr_src, const float* __restrict__ att2,
    const float* __restrict__ b2, float* __restrict__ out)
{
    const int wv = threadIdx.x >> 6, lane = threadIdx.x & 63;
    const int i = blockIdx.x * 4 + wv;
    if (i >= N_NODES) return;
    const int s0 = row_start[i], s1 = row_start[i + 1];
    const bool act = lane < NCLS;
    const float xr = act ? xlr2[(size_t)i * 80 + 40 + lane] : 0.f;
    const float att = act ? att2[lane] : 0.f;
    float m_run = -__builtin_inff(), l_run = 0.f, acc = 0.f;
    for (int e = s0; e < s1; e++) {
        int src = csr_src[e];
        float xl = act ? xlr2[(size_t)src * 80 + lane] : 0.f;
        float v = lrelu(xl + xr) * att;
        #pragma unroll
        for (int off = 32; off; off >>= 1) v += __shfl_xor(v, off, 64);
        float m_new = fmaxf(m_run, v);
        float sc = __expf(m_run - m_new);
        float p = __expf(v - m_new);
        acc = acc * sc + p * xl;
        l_run = l_run * sc + p;
        m_run = m_new;
    }
    if (act) out[(size_t)i * 40 + lane] = acc / (l_run + SM_EPS) + b2[lane];
}

// ---------------------------------------------------------------- launch
extern "C" void kernel_launch(void* const* d_in, const int* in_sizes, int n_in,
                              void* d_out, int out_size, void* d_ws, size_t ws_size,
                              hipStream_t stream)
{
    const float* x     = (const float*)d_in[0];
    const int*   ei    = (const int*)d_in[1];
    const float* Wl1   = (const float*)d_in[2];
    const float* Wr1   = (const float*)d_in[3];
    const float* att1  = (const float*)d_in[4];
    const float* b1    = (const float*)d_in[5];
    const float* gamma1= (const float*)d_in[6];
    const float* beta1 = (const float*)d_in[7];
    const float* Wl2   = (const float*)d_in[8];
    const float* Wr2   = (const float*)d_in[9];
    const float* att2  = (const float*)d_in[10];
    const float* b2    = (const float*)d_in[11];
    float* out = (float*)d_out;

    char* ws = (char*)d_ws;
    size_t off = 0;
    float* xlr1    = (float*)(ws + off); off += (size_t)N_NODES * 512 * 4;  // 102.4 MB
    float* h1      = (float*)(ws + off); off += (size_t)N_NODES * 256 * 4;  //  51.2 MB
    int*   csr_src = (int*)  (ws + off); off += (size_t)ET * 4;             //   3.4 MB
    int*   row_st  = (int*)  (ws + off); off += (size_t)(N_NODES + 1) * 4;
    int*   cursor  = (int*)  (ws + off); off += (size_t)N_NODES * 4;
    int*   deg     = (int*)  (ws + off); off += (size_t)N_NODES * 4;
    float* bn_sum  = (float*)(ws + off); off += 256 * 4;
    float* bn_sumsq= (float*)(ws + off); off += 256 * 4;
    float* bn_g    = (float*)(ws + off); off += 256 * 4;
    float* bn_b    = (float*)(ws + off); off += 256 * 4;
    float* xlr2 = xlr1;   // xlr1 is dead after k_node1; reuse for layer-2 (16 MB)

    hipMemsetAsync(deg, 0, (size_t)N_NODES * 4, stream);
    hipMemsetAsync(bn_sum, 0, 512 * 4, stream);   // bn_sum + bn_sumsq contiguous

    k_deg<<<(ET + 255) / 256, 256, 0, stream>>>(ei, deg);
    k_scan<<<1, 1024, 0, stream>>>(deg, row_st, cursor);
    k_scatter<<<(ET + 255) / 256, 256, 0, stream>>>(ei, cursor, csr_src);

    dim3 g1((N_NODES + GBM - 1) / GBM, (512 + GBN - 1) / GBN);
    k_gemm<<<g1, 256, 0, stream>>>(x, Wl1, Wr1, xlr1, N_NODES, IN_DIM, 256, 512,
                                   nullptr, nullptr, 0);
    k_node1<<<N_NODES, 256, 0, stream>>>(xlr1, row_st, csr_src, att1, b1, h1);

    k_bnstats<<<250, 256, 0, stream>>>(h1, bn_sum, bn_sumsq);
    k_bnfinal<<<1, 256, 0, stream>>>(bn_sum, bn_sumsq, gamma1, beta1, bn_g, bn_b);

    dim3 g2((N_NODES + GBM - 1) / GBM, 1);
    k_gemm<<<g2, 256, 0, stream>>>(h1, Wl2, Wr2, xlr2, N_NODES, D1, 40, 80,
                                   bn_g, bn_b, 1);
    k_node2<<<(N_NODES + 3) / 4, 256, 0, stream>>>(xlr2, row_st, csr_src, att2, b2, out);
}

// Round 2
// 896.903 us; speedup vs baseline: 1.1921x; 1.1921x over previous
//
#include <hip/hip_runtime.h>
#include <math.h>

#define N_NODES 50000
#define N_EDGES 800000
#define ET (N_EDGES + N_NODES)      // 850000 edges incl. self-loops
#define IN_DIM 128
#define HID 64
#define HEADS 4
#define D1 256                      // HID*HEADS
#define NCLS 40
#define NEG_SLOPE 0.2f
#define BN_EPS 1e-5f
#define SM_EPS 1e-16f

__device__ __forceinline__ float eluf(float x) { return x > 0.f ? x : expm1f(x); }
__device__ __forceinline__ float lrelu(float x) { return x >= 0.f ? x : NEG_SLOPE * x; }

// ---------------------------------------------------------------- CSR build
__global__ void k_deg(const int* __restrict__ ei, int* __restrict__ deg) {
    int e = blockIdx.x * blockDim.x + threadIdx.x;
    if (e >= ET) return;
    int dst = (e < N_EDGES) ? ei[N_EDGES + e] : (e - N_EDGES);
    atomicAdd(&deg[dst], 1);
}

// single-block exclusive scan (wave shuffle scan + cross-wave LDS), 1024 thr
__global__ __launch_bounds__(1024) void k_scan(const int* __restrict__ deg,
                                               int* __restrict__ row_start,
                                               int* __restrict__ cursor) {
    __shared__ int wsum[16];
    __shared__ int chunk_tot;
    __shared__ int carry_sh;
    const int t = threadIdx.x;
    const int w = t >> 6, lane = t & 63;
    if (t == 0) carry_sh = 0;
    __syncthreads();
    for (int base = 0; base < N_NODES; base += 1024) {
        const int idx = base + t;
        int v = (idx < N_NODES) ? deg[idx] : 0;
        int s = v;                       // inclusive wave scan
        #pragma unroll
        for (int off = 1; off < 64; off <<= 1) {
            int y = __shfl_up(s, off, 64);
            if (lane >= off) s += y;
        }
        if (lane == 63) wsum[w] = s;
        __syncthreads();
        if (t < 16) {                    // scan the 16 wave totals
            int x = wsum[t];
            int sc = x;
            #pragma unroll
            for (int off = 1; off < 16; off <<= 1) {
                int y = __shfl_up(sc, off, 64);
                if (t >= off) sc += y;
            }
            wsum[t] = sc - x;            // exclusive wave offset
            if (t == 15) chunk_tot = sc;
        }
        __syncthreads();
        const int excl = carry_sh + wsum[w] + (s - v);
        if (idx < N_NODES) { row_start[idx] = excl; cursor[idx] = excl; }
        __syncthreads();
        if (t == 0) carry_sh += chunk_tot;
    }
    __syncthreads();
    if (t == 0) row_start[N_NODES] = carry_sh;
}

__global__ void k_scatter(const int* __restrict__ ei, int* __restrict__ cursor,
                          int* __restrict__ csr_src) {
    int e = blockIdx.x * blockDim.x + threadIdx.x;
    if (e >= ET) return;
    int src, dst;
    if (e < N_EDGES) { src = ei[e]; dst = ei[N_EDGES + e]; }
    else             { src = dst = e - N_EDGES; }
    int pos = atomicAdd(&cursor[dst], 1);
    csr_src[pos] = src;
}

// ---------------------------------------------------------------- GEMM
// C[M x ncols] = op(A[M x K]) @ [B1 | B2]   (B1,B2 each K x w, ncols = 2w)
// op = identity, or fused batchnorm-affine + ELU when fuse != 0.
#define GBM 128
#define GBN 128
#define GBK 16
__global__ __launch_bounds__(256) void k_gemm(
    const float* __restrict__ A, const float* __restrict__ B1,
    const float* __restrict__ B2, float* __restrict__ C,
    int M, int K, int w, int ncols,
    const float* __restrict__ bn_g, const float* __restrict__ bn_b, int fuse)
{
    __shared__ float As[GBK][GBM + 4];
    __shared__ float Bs[GBK][GBN + 4];
    __shared__ float gsh[256], bsh[256];
    const int t = threadIdx.x;
    const int i0 = blockIdx.x * GBM;
    const int j0 = blockIdx.y * GBN;
    if (fuse && t < K) { gsh[t] = bn_g[t]; bsh[t] = bn_b[t]; }
    __syncthreads();

    float acc[8][8];
    #pragma unroll
    for (int a = 0; a < 8; a++)
        #pragma unroll
        for (int b = 0; b < 8; b++) acc[a][b] = 0.f;
    const int tm = (t >> 4) * 8;
    const int tn = (t & 15) * 8;

    for (int kt = 0; kt < K; kt += GBK) {
        #pragma unroll
        for (int i = 0; i < 2; i++) {
            int f = t + i * 256;          // 0..511
            int m = f >> 2;
            int kq = (f & 3) << 2;
            int row = i0 + m;
            float4 v = make_float4(0.f, 0.f, 0.f, 0.f);
            if (row < M) v = *(const float4*)&A[(size_t)row * K + kt + kq];
            if (fuse) {
                int k = kt + kq;
                v.x = eluf(gsh[k + 0] * v.x + bsh[k + 0]);
                v.y = eluf(gsh[k + 1] * v.y + bsh[k + 1]);
                v.z = eluf(gsh[k + 2] * v.z + bsh[k + 2]);
                v.w = eluf(gsh[k + 3] * v.w + bsh[k + 3]);
            }
            As[kq + 0][m] = v.x; As[kq + 1][m] = v.y;
            As[kq + 2][m] = v.z; As[kq + 3][m] = v.w;
        }
        #pragma unroll
        for (int i = 0; i < 8; i++) {
            int f = t + i * 256;          // 0..2047
            int kk = f >> 7;
            int j = f & 127;
            int col = j0 + j;
            float v = 0.f;
            if (col < ncols) {
                int kg = kt + kk;
                v = (col < w) ? B1[(size_t)kg * w + col]
                              : B2[(size_t)kg * w + (col - w)];
            }
            Bs[kk][j] = v;
        }
        __syncthreads();
        #pragma unroll
        for (int kk = 0; kk < GBK; kk++) {
            float4 a0 = *(const float4*)&As[kk][tm];
            float4 a1 = *(const float4*)&As[kk][tm + 4];
            float4 b0 = *(const float4*)&Bs[kk][tn];
            float4 b1 = *(const float4*)&Bs[kk][tn + 4];
            float av[8] = {a0.x, a0.y, a0.z, a0.w, a1.x, a1.y, a1.z, a1.w};
            float bv[8] = {b0.x, b0.y, b0.z, b0.w, b1.x, b1.y, b1.z, b1.w};
            #pragma unroll
            for (int a = 0; a < 8; a++)
                #pragma unroll
                for (int b = 0; b < 8; b++) acc[a][b] += av[a] * bv[b];
        }
        __syncthreads();
    }
    #pragma unroll
    for (int a = 0; a < 8; a++) {
        int row = i0 + tm + a;
        if (row >= M) continue;
        #pragma unroll
        for (int b = 0; b < 8; b += 4) {
            int col = j0 + tn + b;
            if (col + 3 < ncols) {
                *(float4*)&C[(size_t)row * ncols + col] =
                    make_float4(acc[a][b], acc[a][b + 1], acc[a][b + 2], acc[a][b + 3]);
            }
        }
    }
}

// ---------------------------------------------------------------- layer-1 node kernel
// One block (256 thr = 4 waves, wave h = head h) per dst node.
// R1->R2: transposed logit pass. Old version did a 6-step shuffle reduce PER
// EDGE (96 ds_swizzle / chunk / wave) and was LDS-pipe-bound (VALUBusy 52%).
// Now: lane (qe=lane>>2, qq=lane&3) dots 16 channels of edge qe via 4
// ds_read_b128 (row stride 260 -> 4-way conflict only), then 2 shuffle steps.
// Staging is float4 (global_load_dwordx4 + ds_write_b128, conflict-free).
// Softmax bookkeeping is done per-thread in registers from 4 broadcast
// float4 reads of the logit row (wave-uniform, zero extra LDS pressure).
#define CH1 16
#define XLS 260   // padded LDS row stride in floats (16B-aligned, breaks pow2)
__global__ __launch_bounds__(256) void k_node1(
    const float* __restrict__ xlr, const int* __restrict__ row_start,
    const int* __restrict__ csr_src, const float* __restrict__ att1,
    const float* __restrict__ b1, float* __restrict__ h1)
{
    __shared__ __align__(16) float xl_sh[CH1 * XLS];   // 16.6 KB
    __shared__ __align__(16) float xr_sh[D1];
    __shared__ __align__(16) float att_sh[D1];
    __shared__ __align__(16) float p_sh[HEADS][CH1];
    __shared__ int src_sh[CH1];
    const int i = blockIdx.x;
    const int t = threadIdx.x;
    const int h = t >> 6, lane = t & 63;
    const int qe = lane >> 2;        // edge slot in transposed logit pass
    const int qq = lane & 3;         // channel-quad within the head
    const int s0 = row_start[i], s1 = row_start[i + 1];
    xr_sh[t] = xlr[(size_t)i * 512 + 256 + t];
    att_sh[t] = att1[t];
    const float bvv = b1[t];
    __syncthreads();

    // per-lane transposed copies of xr/att: channels h*64 + qq*16 + k
    float xr_t[16], at_t[16];
    {
        const float* xrp = &xr_sh[h * 64 + qq * 16];
        const float* atp = &att_sh[h * 64 + qq * 16];
        #pragma unroll
        for (int k = 0; k < 16; k += 4) {
            float4 a = *(const float4*)&xrp[k];
            float4 b = *(const float4*)&atp[k];
            xr_t[k + 0] = a.x; xr_t[k + 1] = a.y; xr_t[k + 2] = a.z; xr_t[k + 3] = a.w;
            at_t[k + 0] = b.x; at_t[k + 1] = b.y; at_t[k + 2] = b.z; at_t[k + 3] = b.w;
        }
    }

    float acc = 0.f;
    float m_run = -__builtin_inff(), l_run = 0.f;

    for (int base = s0; base < s1; base += CH1) {
        const int cnt = min(CH1, s1 - base);
        __syncthreads();                       // prev chunk's agg reads done
        if (t < cnt) src_sh[t] = csr_src[base + t];
        __syncthreads();
        // stage: wave h loads edges {h, 4+h, 8+h, 12+h}, 1 KB each, float4
        #pragma unroll
        for (int r = 0; r < 4; r++) {
            int e = r * 4 + h;
            if (e < cnt) {                      // wave-uniform branch
                float4 v = *(const float4*)&xlr[(size_t)src_sh[e] * 512 + 4 * lane];
                *(float4*)&xl_sh[e * XLS + 4 * lane] = v;
            }
        }
        __syncthreads();
        // transposed logit: 4 b128 reads + 16 fma-ish per lane, 2 shuffles
        float dot = 0.f;
        {
            const float* xp = &xl_sh[qe * XLS + h * 64 + qq * 16];
            #pragma unroll
            for (int k = 0; k < 16; k += 4) {
                float4 v = *(const float4*)&xp[k];
                dot += lrelu(v.x + xr_t[k + 0]) * at_t[k + 0];
                dot += lrelu(v.y + xr_t[k + 1]) * at_t[k + 1];
                dot += lrelu(v.z + xr_t[k + 2]) * at_t[k + 2];
                dot += lrelu(v.w + xr_t[k + 3]) * at_t[k + 3];
            }
        }
        dot += __shfl_xor(dot, 1, 64);
        dot += __shfl_xor(dot, 2, 64);
        if (qq == 0) p_sh[h][qe] = (qe < cnt) ? dot : -__builtin_inff();
        // wave-local write->read; compiler inserts the lgkmcnt wait (same
        // pattern as R1's p_sh stash — verified passing)
        float4 L0 = *(const float4*)&p_sh[h][0];
        float4 L1 = *(const float4*)&p_sh[h][4];
        float4 L2 = *(const float4*)&p_sh[h][8];
        float4 L3 = *(const float4*)&p_sh[h][12];
        float lg[16] = {L0.x, L0.y, L0.z, L0.w, L1.x, L1.y, L1.z, L1.w,
                        L2.x, L2.y, L2.z, L2.w, L3.x, L3.y, L3.z, L3.w};
        float m_chunk = lg[0];
        #pragma unroll
        for (int e = 1; e < 16; e++) m_chunk = fmaxf(m_chunk, lg[e]);
        const float m_new = fmaxf(m_run, m_chunk);
        const float scale = __expf(m_run - m_new);   // exp(-inf)=0 first time
        float p[16];
        float lsum = 0.f;
        #pragma unroll
        for (int e = 0; e < 16; e++) { p[e] = __expf(lg[e] - m_new); lsum += p[e]; }
        acc *= scale;
        l_run = l_run * scale + lsum;
        m_run = m_new;
        // aggregation: p[e]==0 for e>=cnt, but stale xl_sh could be NaN ->
        // select (not fmac) so masked lanes contribute an exact 0
        #pragma unroll
        for (int e = 0; e < 16; e++) {
            float v = p[e] * xl_sh[e * XLS + t];
            acc += (e < cnt) ? v : 0.f;
        }
    }
    h1[(size_t)i * 256 + t] = acc / (l_run + SM_EPS) + bvv;
}

// ---------------------------------------------------------------- batchnorm
__global__ void k_bnstats(const float* __restrict__ h1, float* __restrict__ bn_sum,
                          float* __restrict__ bn_sumsq) {
    const int t = threadIdx.x;           // 256 = one feature per thread
    const int rows_per = (N_NODES + gridDim.x - 1) / gridDim.x;
    const int r0 = blockIdx.x * rows_per;
    const int r1 = min(N_NODES, r0 + rows_per);
    float s = 0.f, s2 = 0.f;
    for (int r = r0; r < r1; r++) {
        float v = h1[(size_t)r * 256 + t];
        s += v; s2 += v * v;
    }
    atomicAdd(&bn_sum[t], s);
    atomicAdd(&bn_sumsq[t], s2);
}

__global__ void k_bnfinal(const float* __restrict__ bn_sum, const float* __restrict__ bn_sumsq,
                          const float* __restrict__ gamma, const float* __restrict__ beta,
                          float* __restrict__ bn_g, float* __restrict__ bn_b) {
    const int t = threadIdx.x;
    float mean = bn_sum[t] * (1.f / N_NODES);
    float var = bn_sumsq[t] * (1.f / N_NODES) - mean * mean;
    float g = gamma[t] * rsqrtf(var + BN_EPS);
    bn_g[t] = g;
    bn_b[t] = beta[t] - g * mean;
}

// ---------------------------------------------------------------- layer-2 node kernel
// One wave per dst node (4 nodes per block); 40 classes live in lanes 0..39.
__global__ __launch_bounds__(256) void k_node2(
    const float* __restrict__ xlr2, const int* __restrict__ row_start,
    const int* __restrict__ csr_src, const float* __restrict__ att2,
    const float* __restrict__ b2, float* __restrict__ out)
{
    const int wv = threadIdx.x >> 6, lane = threadIdx.x & 63;
    const int i = blockIdx.x * 4 + wv;
    if (i >= N_NODES) return;
    const int s0 = row_start[i], s1 = row_start[i + 1];
    const bool act = lane < NCLS;
    const float xr = act ? xlr2[(size_t)i * 80 + 40 + lane] : 0.f;
    const float att = act ? att2[lane] : 0.f;
    float m_run = -__builtin_inff(), l_run = 0.f, acc = 0.f;
    for (int e = s0; e < s1; e++) {
        int src = csr_src[e];
        float xl = act ? xlr2[(size_t)src * 80 + lane] : 0.f;
        float v = lrelu(xl + xr) * att;
        #pragma unroll
        for (int off = 32; off; off >>= 1) v += __shfl_xor(v, off, 64);
        float m_new = fmaxf(m_run, v);
        float sc = __expf(m_run - m_new);
        float p = __expf(v - m_new);
        acc = acc * sc + p * xl;
        l_run = l_run * sc + p;
        m_run = m_new;
    }
    if (act) out[(size_t)i * 40 + lane] = acc / (l_run + SM_EPS) + b2[lane];
}

// ---------------------------------------------------------------- launch
extern "C" void kernel_launch(void* const* d_in, const int* in_sizes, int n_in,
                              void* d_out, int out_size, void* d_ws, size_t ws_size,
                              hipStream_t stream)
{
    const float* x     = (const float*)d_in[0];
    const int*   ei    = (const int*)d_in[1];
    const float* Wl1   = (const float*)d_in[2];
    const float* Wr1   = (const float*)d_in[3];
    const float* att1  = (const float*)d_in[4];
    const float* b1    = (const float*)d_in[5];
    const float* gamma1= (const float*)d_in[6];
    const float* beta1 = (const float*)d_in[7];
    const float* Wl2   = (const float*)d_in[8];
    const float* Wr2   = (const float*)d_in[9];
    const float* att2  = (const float*)d_in[10];
    const float* b2    = (const float*)d_in[11];
    float* out = (float*)d_out;

    char* ws = (char*)d_ws;
    size_t off = 0;
    float* xlr1    = (float*)(ws + off); off += (size_t)N_NODES * 512 * 4;  // 102.4 MB
    float* h1      = (float*)(ws + off); off += (size_t)N_NODES * 256 * 4;  //  51.2 MB
    int*   csr_src = (int*)  (ws + off); off += (size_t)ET * 4;             //   3.4 MB
    int*   row_st  = (int*)  (ws + off); off += (size_t)(N_NODES + 1) * 4;
    int*   cursor  = (int*)  (ws + off); off += (size_t)N_NODES * 4;
    int*   deg     = (int*)  (ws + off); off += (size_t)N_NODES * 4;
    float* bn_sum  = (float*)(ws + off); off += 256 * 4;
    float* bn_sumsq= (float*)(ws + off); off += 256 * 4;
    float* bn_g    = (float*)(ws + off); off += 256 * 4;
    float* bn_b    = (float*)(ws + off); off += 256 * 4;
    float* xlr2 = xlr1;   // xlr1 dead after k_node1; reuse for layer-2 (16 MB)

    hipMemsetAsync(deg, 0, (size_t)N_NODES * 4, stream);
    hipMemsetAsync(bn_sum, 0, 512 * 4, stream);   // bn_sum + bn_sumsq contiguous

    k_deg<<<(ET + 255) / 256, 256, 0, stream>>>(ei, deg);
    k_scan<<<1, 1024, 0, stream>>>(deg, row_st, cursor);
    k_scatter<<<(ET + 255) / 256, 256, 0, stream>>>(ei, cursor, csr_src);

    dim3 g1((N_NODES + GBM - 1) / GBM, (512 + GBN - 1) / GBN);
    k_gemm<<<g1, 256, 0, stream>>>(x, Wl1, Wr1, xlr1, N_NODES, IN_DIM, 256, 512,
                                   nullptr, nullptr, 0);
    k_node1<<<N_NODES, 256, 0, stream>>>(xlr1, row_st, csr_src, att1, b1, h1);

    k_bnstats<<<250, 256, 0, stream>>>(h1, bn_sum, bn_sumsq);
    k_bnfinal<<<1, 256, 0, stream>>>(bn_sum, bn_sumsq, gamma1, beta1, bn_g, bn_b);

    dim3 g2((N_NODES + GBM - 1) / GBM, 1);
    k_gemm<<<g2, 256, 0, stream>>>(h1, Wl2, Wr2, xlr2, N_NODES, D1, 40, 80,
                                   bn_g, bn_b, 1);
    k_node2<<<(N_NODES + 3) / 4, 256, 0, stream>>>(xlr2, row_st, csr_src, att2, b2, out);
}

// Round 4
// 647.845 us; speedup vs baseline: 1.6505x; 1.3844x over previous
//
#include <hip/hip_runtime.h>
#include <math.h>

#define N_NODES 50000
#define N_EDGES 800000
#define ET (N_EDGES + N_NODES)      // 850000 edges incl. self-loops
#define IN_DIM 128
#define HID 64
#define HEADS 4
#define D1 256                      // HID*HEADS
#define NCLS 40
#define NEG_SLOPE 0.2f
#define BN_EPS 1e-5f
#define SM_EPS 1e-16f

typedef unsigned short ushort_t;
typedef __attribute__((ext_vector_type(8))) short short8;
typedef __attribute__((ext_vector_type(16))) float f32x16;

__device__ __forceinline__ float eluf(float x) { return x > 0.f ? x : expm1f(x); }
__device__ __forceinline__ float lrelu(float x) { return x >= 0.f ? x : NEG_SLOPE * x; }
__device__ __forceinline__ unsigned short f2bf(float f) {   // RNE fp32->bf16
    unsigned int u = __float_as_uint(f);
    u += 0x7fffu + ((u >> 16) & 1u);
    return (unsigned short)(u >> 16);
}

// ---------------------------------------------------------------- CSR build
__global__ void k_deg(const int* __restrict__ ei, int* __restrict__ deg) {
    int e = blockIdx.x * blockDim.x + threadIdx.x;
    if (e >= ET) return;
    int dst = (e < N_EDGES) ? ei[N_EDGES + e] : (e - N_EDGES);
    atomicAdd(&deg[dst], 1);
}

__global__ __launch_bounds__(1024) void k_scan(const int* __restrict__ deg,
                                               int* __restrict__ row_start,
                                               int* __restrict__ cursor) {
    __shared__ int wsum[16];
    __shared__ int chunk_tot;
    __shared__ int carry_sh;
    const int t = threadIdx.x;
    const int w = t >> 6, lane = t & 63;
    if (t == 0) carry_sh = 0;
    __syncthreads();
    for (int base = 0; base < N_NODES; base += 1024) {
        const int idx = base + t;
        int v = (idx < N_NODES) ? deg[idx] : 0;
        int s = v;
        #pragma unroll
        for (int off = 1; off < 64; off <<= 1) {
            int y = __shfl_up(s, off, 64);
            if (lane >= off) s += y;
        }
        if (lane == 63) wsum[w] = s;
        __syncthreads();
        if (t < 16) {
            int x = wsum[t];
            int sc = x;
            #pragma unroll
            for (int off = 1; off < 16; off <<= 1) {
                int y = __shfl_up(sc, off, 64);
                if (t >= off) sc += y;
            }
            wsum[t] = sc - x;
            if (t == 15) chunk_tot = sc;
        }
        __syncthreads();
        const int excl = carry_sh + wsum[w] + (s - v);
        if (idx < N_NODES) { row_start[idx] = excl; cursor[idx] = excl; }
        __syncthreads();
        if (t == 0) carry_sh += chunk_tot;
    }
    __syncthreads();
    if (t == 0) row_start[N_NODES] = carry_sh;
}

__global__ void k_scatter(const int* __restrict__ ei, int* __restrict__ cursor,
                          int* __restrict__ csr_src) {
    int e = blockIdx.x * blockDim.x + threadIdx.x;
    if (e >= ET) return;
    int src, dst;
    if (e < N_EDGES) { src = ei[e]; dst = ei[N_EDGES + e]; }
    else             { src = dst = e - N_EDGES; }
    int pos = atomicAdd(&cursor[dst], 1);
    csr_src[pos] = src;
}

// ---------------------------------------------------------------- converts
__global__ void k_cvt_x(const float* __restrict__ x, ushort_t* __restrict__ xb, int n4) {
    int i = blockIdx.x * blockDim.x + threadIdx.x;
    if (i >= n4) return;
    float4 v = ((const float4*)x)[i];
    ushort4 o;
    o.x = f2bf(v.x); o.y = f2bf(v.y); o.z = f2bf(v.z); o.w = f2bf(v.w);
    ((ushort4*)xb)[i] = o;
}

// BT1[n][k] (512 x 128) = [Wl1 | Wr1]^T  (Wl1, Wr1: 128 x 256)
__global__ void k_cvt_w1(const float* __restrict__ Wl, const float* __restrict__ Wr,
                         ushort_t* __restrict__ BT) {
    int n = blockIdx.x;          // 0..511
    int k = threadIdx.x;         // 0..127
    float v = (n < 256) ? Wl[k * 256 + n] : Wr[k * 256 + (n - 256)];
    BT[n * 128 + k] = f2bf(v);
}

// BT2[n][k] (128 x 256, rows 80..127 zero) = [Wl2 | Wr2]^T  (Wl2, Wr2: 256 x 40)
__global__ void k_cvt_w2(const float* __restrict__ Wl, const float* __restrict__ Wr,
                         ushort_t* __restrict__ BT) {
    int n = blockIdx.x;          // 0..127
    int k = threadIdx.x;         // 0..255
    float v = 0.f;
    if (n < 40)      v = Wl[k * 40 + n];
    else if (n < 80) v = Wr[k * 40 + (n - 40)];
    BT[n * 256 + k] = f2bf(v);
}

// h1b = bf16(elu(bn_g*h1 + bn_b)); 4 elems/thread, 256 cols
__global__ void k_cvt_h(const float* __restrict__ h1, const float* __restrict__ g,
                        const float* __restrict__ b, ushort_t* __restrict__ h1b) {
    int i = blockIdx.x * blockDim.x + threadIdx.x;   // elem-quad index
    int c0 = (threadIdx.x * 4) & 255;                // block = 1024 elems = 4 rows
    float4 v = ((const float4*)h1)[i];
    ushort4 o;
    o.x = f2bf(eluf(g[c0 + 0] * v.x + b[c0 + 0]));
    o.y = f2bf(eluf(g[c0 + 1] * v.y + b[c0 + 1]));
    o.z = f2bf(eluf(g[c0 + 2] * v.z + b[c0 + 2]));
    o.w = f2bf(eluf(g[c0 + 3] * v.w + b[c0 + 3]));
    ((ushort4*)h1b)[i] = o;
}

// ---------------------------------------------------------------- MFMA GEMM
// C[M x ldc](fp32) = A[M x K](bf16) @ BT[N_pad x K](bf16)^T
// 128x128 block tile, 4 waves in 2x2, 64x64 wave tile of 32x32 MFMAs, BK=64.
// LDS layout: per row 8 16B-chunks, chunk slot c' = c ^ (m&7):
//  - staging ds_write_b128 at contiguous slots -> conflict-free
//  - fragment ds_read_b128: 8 consecutive rows hit all 8 bank-quads (free)
// R3->R4: global_load_lds async DMA (suspected crash source) replaced by a
// register round-trip (short8 global load -> ds_write_b128). Loads are
// issued BEFORE the barrier so they overlap the previous iter's MFMAs.
#define MBM 128
#define MBN 128
#define MBK 64
__global__ __launch_bounds__(256) void k_mgemm(
    const ushort_t* __restrict__ A, const ushort_t* __restrict__ BT,
    float* __restrict__ C, int M, int K, int N, int ldc)
{
    __shared__ __align__(16) ushort_t Al[MBM * MBK];   // 16 KB
    __shared__ __align__(16) ushort_t Bl[MBN * MBK];   // 16 KB
    const int t = threadIdx.x;
    const int w = t >> 6, L = t & 63;
    const int i0 = blockIdx.x * MBM;
    const int j0 = blockIdx.y * MBN;
    const int wm = (w >> 1) * 64, wn = (w & 1) * 64;
    const int l31 = L & 31, half = L >> 5;

    // per-thread staging geometry (slot s -> row m, swizzled chunk c)
    int sm[4], sca[4], scb[4];
    #pragma unroll
    for (int r = 0; r < 4; r++) {
        int s = (r * 4 + w) * 64 + L;      // chunk slot 0..1023
        int m = s >> 3;
        sm[r] = m;
        sca[r] = (s & 7) ^ (m & 7);
        scb[r] = sca[r];
    }

    f32x16 acc[2][2];
    #pragma unroll
    for (int a = 0; a < 2; a++)
        #pragma unroll
        for (int b = 0; b < 2; b++)
            #pragma unroll
            for (int r = 0; r < 16; r++) acc[a][b][r] = 0.f;

    for (int kt = 0; kt < K; kt += MBK) {
        // issue global loads first (overlaps previous iteration's compute)
        short8 sa[4], sb[4];
        #pragma unroll
        for (int r = 0; r < 4; r++) {
            int row = i0 + sm[r]; if (row >= M) row = M - 1;
            sa[r] = *(const short8*)&A[(size_t)row * K + kt + sca[r] * 8];
            sb[r] = *(const short8*)&BT[(size_t)(j0 + sm[r]) * K + kt + scb[r] * 8];
        }
        __syncthreads();                   // prev iter's frag reads done
        #pragma unroll
        for (int r = 0; r < 4; r++) {
            int s = (r * 4 + w) * 64 + L;
            *(short8*)&Al[s * 8] = sa[r];
            *(short8*)&Bl[s * 8] = sb[r];
        }
        __syncthreads();
        #pragma unroll
        for (int ks = 0; ks < 4; ks++) {   // 4 k-steps of 16
            short8 af[2], bfr[2];
            #pragma unroll
            for (int mt = 0; mt < 2; mt++) {
                int m = wm + mt * 32 + l31;
                int c = (ks * 2 + half) ^ (m & 7);
                af[mt] = *(const short8*)&Al[(m * 8 + c) * 8];
            }
            #pragma unroll
            for (int nt = 0; nt < 2; nt++) {
                int n = wn + nt * 32 + l31;
                int c = (ks * 2 + half) ^ (n & 7);
                bfr[nt] = *(const short8*)&Bl[(n * 8 + c) * 8];
            }
            #pragma unroll
            for (int mt = 0; mt < 2; mt++)
                #pragma unroll
                for (int nt = 0; nt < 2; nt++)
                    acc[mt][nt] = __builtin_amdgcn_mfma_f32_32x32x16_bf16(
                        af[mt], bfr[nt], acc[mt][nt], 0, 0, 0);
        }
    }
    // epilogue: C/D layout col = lane&31, row = (r&3) + 8*(r>>2) + 4*half
    #pragma unroll
    for (int mt = 0; mt < 2; mt++)
        #pragma unroll
        for (int nt = 0; nt < 2; nt++) {
            int col = j0 + wn + nt * 32 + l31;
            int rbase = i0 + wm + mt * 32 + 4 * half;
            if (col < N) {
                #pragma unroll
                for (int r = 0; r < 16; r++) {
                    int row = rbase + (r & 3) + 8 * (r >> 2);
                    if (row < M) C[(size_t)row * ldc + col] = acc[mt][nt][r];
                }
            }
        }
}

// ---------------------------------------------------------------- layer-1 node kernel
#define CH1 16
#define XLS 260   // padded LDS row stride in floats
__global__ __launch_bounds__(256) void k_node1(
    const float* __restrict__ xlr, const int* __restrict__ row_start,
    const int* __restrict__ csr_src, const float* __restrict__ att1,
    const float* __restrict__ b1, float* __restrict__ h1)
{
    __shared__ __align__(16) float xl_sh[CH1 * XLS];   // 16.6 KB
    __shared__ __align__(16) float xr_sh[D1];
    __shared__ __align__(16) float att_sh[D1];
    __shared__ __align__(16) float p_sh[HEADS][CH1];
    __shared__ int src_sh[CH1];
    const int i = blockIdx.x;
    const int t = threadIdx.x;
    const int h = t >> 6, lane = t & 63;
    const int qe = lane >> 2;
    const int qq = lane & 3;
    const int s0 = row_start[i], s1 = row_start[i + 1];
    xr_sh[t] = xlr[(size_t)i * 512 + 256 + t];
    att_sh[t] = att1[t];
    const float bvv = b1[t];
    __syncthreads();

    float xr_t[16], at_t[16];
    {
        const float* xrp = &xr_sh[h * 64 + qq * 16];
        const float* atp = &att_sh[h * 64 + qq * 16];
        #pragma unroll
        for (int k = 0; k < 16; k += 4) {
            float4 a = *(const float4*)&xrp[k];
            float4 b = *(const float4*)&atp[k];
            xr_t[k + 0] = a.x; xr_t[k + 1] = a.y; xr_t[k + 2] = a.z; xr_t[k + 3] = a.w;
            at_t[k + 0] = b.x; at_t[k + 1] = b.y; at_t[k + 2] = b.z; at_t[k + 3] = b.w;
        }
    }

    float acc = 0.f;
    float m_run = -__builtin_inff(), l_run = 0.f;

    for (int base = s0; base < s1; base += CH1) {
        const int cnt = min(CH1, s1 - base);
        __syncthreads();
        if (t < cnt) src_sh[t] = csr_src[base + t];
        __syncthreads();
        #pragma unroll
        for (int r = 0; r < 4; r++) {
            int e = r * 4 + h;
            if (e < cnt) {
                float4 v = *(const float4*)&xlr[(size_t)src_sh[e] * 512 + 4 * lane];
                *(float4*)&xl_sh[e * XLS + 4 * lane] = v;
            }
        }
        __syncthreads();
        float dot = 0.f;
        {
            const float* xp = &xl_sh[qe * XLS + h * 64 + qq * 16];
            #pragma unroll
            for (int k = 0; k < 16; k += 4) {
                float4 v = *(const float4*)&xp[k];
                dot += lrelu(v.x + xr_t[k + 0]) * at_t[k + 0];
                dot += lrelu(v.y + xr_t[k + 1]) * at_t[k + 1];
                dot += lrelu(v.z + xr_t[k + 2]) * at_t[k + 2];
                dot += lrelu(v.w + xr_t[k + 3]) * at_t[k + 3];
            }
        }
        dot += __shfl_xor(dot, 1, 64);
        dot += __shfl_xor(dot, 2, 64);
        if (qq == 0) p_sh[h][qe] = (qe < cnt) ? dot : -__builtin_inff();
        float4 L0 = *(const float4*)&p_sh[h][0];
        float4 L1 = *(const float4*)&p_sh[h][4];
        float4 L2 = *(const float4*)&p_sh[h][8];
        float4 L3 = *(const float4*)&p_sh[h][12];
        float lg[16] = {L0.x, L0.y, L0.z, L0.w, L1.x, L1.y, L1.z, L1.w,
                        L2.x, L2.y, L2.z, L2.w, L3.x, L3.y, L3.z, L3.w};
        float m_chunk = lg[0];
        #pragma unroll
        for (int e = 1; e < 16; e++) m_chunk = fmaxf(m_chunk, lg[e]);
        const float m_new = fmaxf(m_run, m_chunk);
        const float scale = __expf(m_run - m_new);
        float p[16];
        float lsum = 0.f;
        #pragma unroll
        for (int e = 0; e < 16; e++) { p[e] = __expf(lg[e] - m_new); lsum += p[e]; }
        acc *= scale;
        l_run = l_run * scale + lsum;
        m_run = m_new;
        #pragma unroll
        for (int e = 0; e < 16; e++) {
            float v = p[e] * xl_sh[e * XLS + t];
            acc += (e < cnt) ? v : 0.f;
        }
    }
    h1[(size_t)i * 256 + t] = acc / (l_run + SM_EPS) + bvv;
}

// ---------------------------------------------------------------- batchnorm
__global__ void k_bnstats(const float* __restrict__ h1, float* __restrict__ bn_sum,
                          float* __restrict__ bn_sumsq) {
    const int t = threadIdx.x;
    const int rows_per = (N_NODES + gridDim.x - 1) / gridDim.x;
    const int r0 = blockIdx.x * rows_per;
    const int r1 = min(N_NODES, r0 + rows_per);
    float s = 0.f, s2 = 0.f;
    for (int r = r0; r < r1; r++) {
        float v = h1[(size_t)r * 256 + t];
        s += v; s2 += v * v;
    }
    atomicAdd(&bn_sum[t], s);
    atomicAdd(&bn_sumsq[t], s2);
}

__global__ void k_bnfinal(const float* __restrict__ bn_sum, const float* __restrict__ bn_sumsq,
                          const float* __restrict__ gamma, const float* __restrict__ beta,
                          float* __restrict__ bn_g, float* __restrict__ bn_b) {
    const int t = threadIdx.x;
    float mean = bn_sum[t] * (1.f / N_NODES);
    float var = bn_sumsq[t] * (1.f / N_NODES) - mean * mean;
    float g = gamma[t] * rsqrtf(var + BN_EPS);
    bn_g[t] = g;
    bn_b[t] = beta[t] - g * mean;
}

// ---------------------------------------------------------------- layer-2 node kernel
__global__ __launch_bounds__(256) void k_node2(
    const float* __restrict__ xlr2, const int* __restrict__ row_start,
    const int* __restrict__ csr_src, const float* __restrict__ att2,
    const float* __restrict__ b2, float* __restrict__ out)
{
    const int wv = threadIdx.x >> 6, lane = threadIdx.x & 63;
    const int i = blockIdx.x * 4 + wv;
    if (i >= N_NODES) return;
    const int s0 = row_start[i], s1 = row_start[i + 1];
    const bool act = lane < NCLS;
    const float xr = act ? xlr2[(size_t)i * 80 + 40 + lane] : 0.f;
    const float att = act ? att2[lane] : 0.f;
    float m_run = -__builtin_inff(), l_run = 0.f, acc = 0.f;
    for (int e = s0; e < s1; e++) {
        int src = csr_src[e];
        float xl = act ? xlr2[(size_t)src * 80 + lane] : 0.f;
        float v = lrelu(xl + xr) * att;
        #pragma unroll
        for (int off = 32; off; off >>= 1) v += __shfl_xor(v, off, 64);
        float m_new = fmaxf(m_run, v);
        float sc = __expf(m_run - m_new);
        float p = __expf(v - m_new);
        acc = acc * sc + p * xl;
        l_run = l_run * sc + p;
        m_run = m_new;
    }
    if (act) out[(size_t)i * 40 + lane] = acc / (l_run + SM_EPS) + b2[lane];
}

// ---------------------------------------------------------------- launch
static inline size_t align_up(size_t v, size_t a) { return (v + a - 1) & ~(a - 1); }

extern "C" void kernel_launch(void* const* d_in, const int* in_sizes, int n_in,
                              void* d_out, int out_size, void* d_ws, size_t ws_size,
                              hipStream_t stream)
{
    const float* x     = (const float*)d_in[0];
    const int*   ei    = (const int*)d_in[1];
    const float* Wl1   = (const float*)d_in[2];
    const float* Wr1   = (const float*)d_in[3];
    const float* att1  = (const float*)d_in[4];
    const float* b1    = (const float*)d_in[5];
    const float* gamma1= (const float*)d_in[6];
    const float* beta1 = (const float*)d_in[7];
    const float* Wl2   = (const float*)d_in[8];
    const float* Wr2   = (const float*)d_in[9];
    const float* att2  = (const float*)d_in[10];
    const float* b2    = (const float*)d_in[11];
    float* out = (float*)d_out;

    char* ws = (char*)d_ws;
    size_t off = 0;
    float* xlr1    = (float*)(ws + off); off += (size_t)N_NODES * 512 * 4;  // 102.4 MB
    float* h1      = (float*)(ws + off); off += (size_t)N_NODES * 256 * 4;  //  51.2 MB
    int*   csr_src = (int*)  (ws + off); off += align_up((size_t)ET * 4, 256);
    int*   row_st  = (int*)  (ws + off); off += align_up((size_t)(N_NODES + 1) * 4, 256);
    int*   cursor  = (int*)  (ws + off); off += align_up((size_t)N_NODES * 4, 256);
    int*   deg     = (int*)  (ws + off); off += align_up((size_t)N_NODES * 4, 256);
    float* bn_sum  = (float*)(ws + off); off += 256 * 4;
    float* bn_sumsq= (float*)(ws + off); off += 256 * 4;
    float* bn_g    = (float*)(ws + off); off += 256 * 4;
    float* bn_b    = (float*)(ws + off); off += 256 * 4;
    ushort_t* BT1  = (ushort_t*)(ws + off); off += align_up((size_t)512 * 128 * 2, 256);
    ushort_t* BT2  = (ushort_t*)(ws + off); off += align_up((size_t)128 * 256 * 2, 256);
    // overlapped scratch (stream-ordered lifetimes, no ws growth):
    float*    xlr2 = xlr1;                               // L2 [xl|xr], 16 MB
    ushort_t* h1b  = (ushort_t*)((char*)xlr1 + (32u << 20)); // 25.6 MB, after node1
    ushort_t* xb   = (ushort_t*)h1;                      // 12.8 MB, dead before node1

    hipMemsetAsync(deg, 0, (size_t)N_NODES * 4, stream);
    hipMemsetAsync(bn_sum, 0, 512 * 4, stream);   // bn_sum + bn_sumsq contiguous

    k_deg<<<(ET + 255) / 256, 256, 0, stream>>>(ei, deg);
    k_scan<<<1, 1024, 0, stream>>>(deg, row_st, cursor);
    k_scatter<<<(ET + 255) / 256, 256, 0, stream>>>(ei, cursor, csr_src);

    k_cvt_x<<<(N_NODES * IN_DIM / 4 + 255) / 256, 256, 0, stream>>>(x, xb, N_NODES * IN_DIM / 4);
    k_cvt_w1<<<512, 128, 0, stream>>>(Wl1, Wr1, BT1);
    k_cvt_w2<<<128, 256, 0, stream>>>(Wl2, Wr2, BT2);

    dim3 g1((N_NODES + MBM - 1) / MBM, 512 / MBN);
    k_mgemm<<<g1, 256, 0, stream>>>(xb, BT1, xlr1, N_NODES, IN_DIM, 512, 512);
    k_node1<<<N_NODES, 256, 0, stream>>>(xlr1, row_st, csr_src, att1, b1, h1);

    k_bnstats<<<250, 256, 0, stream>>>(h1, bn_sum, bn_sumsq);
    k_bnfinal<<<1, 256, 0, stream>>>(bn_sum, bn_sumsq, gamma1, beta1, bn_g, bn_b);
    k_cvt_h<<<(N_NODES * 256 / 4 + 255) / 256, 256, 0, stream>>>(h1, bn_g, bn_b, h1b);

    dim3 g2((N_NODES + MBM - 1) / MBM, 1);
    k_mgemm<<<g2, 256, 0, stream>>>(h1b, BT2, xlr2, N_NODES, D1, 80, 80);
    k_node2<<<(N_NODES + 3) / 4, 256, 0, stream>>>(xlr2, row_st, csr_src, att2, b2, out);
}